// Round 3
// baseline (567.257 us; speedup 1.0000x reference)
//
#include <hip/hip_runtime.h>

typedef __attribute__((ext_vector_type(8))) short short8;
typedef __attribute__((ext_vector_type(4))) float floatx4;
typedef __attribute__((ext_vector_type(4))) unsigned int uintx4;
typedef __attribute__((ext_vector_type(2))) unsigned int uintx2;
typedef __attribute__((ext_vector_type(4))) int intx4;
typedef __attribute__((ext_vector_type(4))) unsigned short ushortx4;

#define NN 8192
#define KIN 512
#define COUT 256
#define SHIFT 16.0f

// ---------- helpers ----------
__device__ __forceinline__ unsigned int f2bf(float f) {
  unsigned int u = __float_as_uint(f);
  return (u + 0x7FFFu + ((u >> 16) & 1u)) >> 16;  // RNE round to bf16
}

__device__ __forceinline__ short8 pack8(const float* p) {
  uintx4 w;
  w.x = f2bf(p[0]) | (f2bf(p[1]) << 16);
  w.y = f2bf(p[2]) | (f2bf(p[3]) << 16);
  w.z = f2bf(p[4]) | (f2bf(p[5]) << 16);
  w.w = f2bf(p[6]) | (f2bf(p[7]) << 16);
  union { uintx4 u; short8 s; } cv; cv.u = w;
  return cv.s;
}

// ---------- K0: compress adj int32 -> row-major bitmask bm[8192][256] u32 ----------
// word idx covers cols [ (idx&255)*32 , +32 ) of row idx>>8; bit c = adj!=0.
// 8192 blocks x 256 thr; each thread: 8 x int4 = 128 B contiguous. Pure stream.
__global__ __launch_bounds__(256)
void k_compress(const int* __restrict__ adj, unsigned int* __restrict__ bm) {
  int idx = blockIdx.x * 256 + threadIdx.x;          // 2M words
  const int* p = adj + (size_t)idx * 32;
  unsigned int m = 0;
#pragma unroll
  for (int k = 0; k < 8; ++k) {
    intx4 v = *(const intx4*)(p + k * 4);
    m |= (v.x != 0 ? 1u : 0u) << (k * 4 + 0);
    m |= (v.y != 0 ? 1u : 0u) << (k * 4 + 1);
    m |= (v.z != 0 ? 1u : 0u) << (k * 4 + 2);
    m |= (v.w != 0 ? 1u : 0u) << (k * 4 + 3);
  }
  bm[idx] = m;
}

// ---------- K1a: cast input fp32 -> bf16 (row-major [8192][512]) ----------
__global__ void k_cast_input(const float* __restrict__ in, ushortx4* __restrict__ out) {
  int idx = blockIdx.x * 256 + threadIdx.x;
  floatx4 v = ((const floatx4*)in)[idx];
  ushortx4 o;
  o.x = (unsigned short)f2bf(v.x);
  o.y = (unsigned short)f2bf(v.y);
  o.z = (unsigned short)f2bf(v.z);
  o.w = (unsigned short)f2bf(v.w);
  out[idx] = o;
}

// ---------- K1b: weights [512][256] fp32 -> wt [256][512] bf16 (transposed) ----------
__global__ void k_prep_w(const float* __restrict__ w, unsigned short* __restrict__ wt) {
  int idx = blockIdx.x * 256 + threadIdx.x;
  int k = idx >> 8, c = idx & 255;
  wt[c * KIN + k] = (unsigned short)f2bf(w[idx]);
}

// ---------- K2: h = X*W via MFMA; emit ht[256][8192] bf16, e1[8192], e2[8192] ----------
__global__ __launch_bounds__(256)
void k_gemm_h(const unsigned short* __restrict__ inA, const unsigned short* __restrict__ wt,
              const float* __restrict__ a1, const float* __restrict__ a2,
              unsigned short* __restrict__ ht, float* __restrict__ e1, float* __restrict__ e2) {
  int wave = threadIdx.x >> 6;
  int lane = threadIdx.x & 63;
  int n = lane & 15, q = lane >> 4;
  int row0 = blockIdx.x * 64 + wave * 16;
  int mrow = row0 + n;

  floatx4 acc[16];
#pragma unroll
  for (int t = 0; t < 16; ++t) acc[t] = (floatx4){0.f, 0.f, 0.f, 0.f};

  for (int kc = 0; kc < KIN / 32; ++kc) {
    int k0 = kc * 32 + q * 8;
    short8 a = *(const short8*)(inA + (size_t)mrow * KIN + k0);
#pragma unroll
    for (int nt = 0; nt < 16; ++nt) {
      short8 b = *(const short8*)(wt + (size_t)(nt * 16 + n) * KIN + k0);
      acc[nt] = __builtin_amdgcn_mfma_f32_16x16x32_bf16(a, b, acc[nt], 0, 0, 0);
    }
  }

  int i0 = row0 + q * 4;
#pragma unroll
  for (int nt = 0; nt < 16; ++nt) {
    int c = nt * 16 + n;
    uintx2 pk;
    pk.x = f2bf(acc[nt][0]) | (f2bf(acc[nt][1]) << 16);
    pk.y = f2bf(acc[nt][2]) | (f2bf(acc[nt][3]) << 16);
    *(uintx2*)(ht + (size_t)c * NN + i0) = pk;
  }

  float s1[4] = {0.f, 0.f, 0.f, 0.f}, s2[4] = {0.f, 0.f, 0.f, 0.f};
#pragma unroll
  for (int nt = 0; nt < 16; ++nt) {
    float w1 = a1[nt * 16 + n];
    float w2 = a2[nt * 16 + n];
#pragma unroll
    for (int r = 0; r < 4; ++r) {
      s1[r] += acc[nt][r] * w1;
      s2[r] += acc[nt][r] * w2;
    }
  }
#pragma unroll
  for (int m = 1; m < 16; m <<= 1) {
#pragma unroll
    for (int r = 0; r < 4; ++r) {
      s1[r] += __shfl_xor(s1[r], m);
      s2[r] += __shfl_xor(s2[r], m);
    }
  }
  if (n == 0) {
#pragma unroll
    for (int r = 0; r < 4; ++r) {
      e1[i0 + r] = s1[r];
      e2[i0 + r] = s2[r];
    }
  }
}

// ---------- K4: masked-softmax attention + PV, bitmask adj ----------
// grid = 64 rowgroups x 8 j-slices = 512 blocks; wave = 32 rows x 256 cols.
// adj comes from the 8 MB L2/L3-resident bitmask; partial stores, no atomics.
__global__ __launch_bounds__(256, 2)
void k_attn_part(const unsigned int* __restrict__ bm, const unsigned short* __restrict__ ht,
                 const float* __restrict__ e1, const float* __restrict__ e2,
                 float* __restrict__ opart, float* __restrict__ Dpart) {
  int b = blockIdx.x;
  int rg = b >> 3, js = b & 7;                       // js = b&7: round-robin XCD gets one slice
  int wave = threadIdx.x >> 6, lane = threadIdx.x & 63;
  int n = lane & 15, q = lane >> 4;
  int rowbase = rg * 128 + wave * 32;

  float e1v0 = e1[rowbase + n];
  float e1v1 = e1[rowbase + 16 + n];

  const unsigned int* bp0 = bm + (size_t)(rowbase + n) * 256 + js * 32;
  const unsigned int* bp1 = bm + (size_t)(rowbase + 16 + n) * 256 + js * 32;

  floatx4 acc[2][16];
#pragma unroll
  for (int t = 0; t < 2; ++t)
#pragma unroll
    for (int nt = 0; nt < 16; ++nt) acc[t][nt] = (floatx4){0.f, 0.f, 0.f, 0.f};

  float d0 = 0.f, d1 = 0.f;
  int jbeg = js * 1024;

  unsigned int W0 = bp0[0];
  unsigned int W1 = bp1[0];

  for (int ch = 0; ch < 32; ++ch) {
    int j0 = jbeg + ch * 32 + q * 8;
    // prefetch next chunk's bitmask words (wrap: harmless reload)
    unsigned int NW0 = bp0[(ch + 1) & 31];
    unsigned int NW1 = bp1[(ch + 1) & 31];

    floatx4 ea = *(const floatx4*)(e2 + j0);
    floatx4 eb = *(const floatx4*)(e2 + j0 + 4);
    float ev[8] = {ea.x, ea.y, ea.z, ea.w, eb.x, eb.y, eb.z, eb.w};

    unsigned int by0 = (W0 >> (q * 8)) & 0xffu;      // 8 adjacency bits for cols j0..j0+7
    unsigned int by1 = (W1 >> (q * 8)) & 0xffu;

    float p0[8], p1[8];
#pragma unroll
    for (int jj = 0; jj < 8; ++jj) {
      float t0 = e1v0 + ev[jj];
      float t1 = e1v1 + ev[jj];
      float f0 = fmaxf(t0, 0.25f * t0);              // leakyrelu
      float f1 = fmaxf(t1, 0.25f * t1);
      float x0 = __expf(f0 - SHIFT);                 // fixed shift: exp <= ~0.14 always
      float x1 = __expf(f1 - SHIFT);
      p0[jj] = ((by0 >> jj) & 1u) ? x0 : 0.f;
      p1[jj] = ((by1 >> jj) & 1u) ? x1 : 0.f;
      d0 += p0[jj];
      d1 += p1[jj];
    }
    short8 af0 = pack8(p0);
    short8 af1 = pack8(p1);

#pragma unroll
    for (int g = 0; g < 2; ++g) {
      short8 bf[8];
#pragma unroll
      for (int t = 0; t < 8; ++t)
        bf[t] = *(const short8*)(ht + (size_t)((g * 8 + t) * 16 + n) * NN + j0);
#pragma unroll
      for (int t = 0; t < 8; ++t) {
        acc[0][g * 8 + t] = __builtin_amdgcn_mfma_f32_16x16x32_bf16(af0, bf[t], acc[0][g * 8 + t], 0, 0, 0);
        acc[1][g * 8 + t] = __builtin_amdgcn_mfma_f32_16x16x32_bf16(af1, bf[t], acc[1][g * 8 + t], 0, 0, 0);
      }
    }

    W0 = NW0; W1 = NW1;
  }

  d0 += __shfl_xor(d0, 16); d0 += __shfl_xor(d0, 32);
  d1 += __shfl_xor(d1, 16); d1 += __shfl_xor(d1, 32);
  if (lane < 16) {
    Dpart[(size_t)js * NN + rowbase + lane] = d0;
    Dpart[(size_t)js * NN + rowbase + 16 + lane] = d1;
  }

  float* op = opart + (size_t)js * NN * COUT;
#pragma unroll
  for (int t2 = 0; t2 < 2; ++t2) {
#pragma unroll
    for (int nt = 0; nt < 16; ++nt) {
#pragma unroll
      for (int r = 0; r < 4; ++r) {
        int i = rowbase + t2 * 16 + q * 4 + r;
        op[(size_t)i * COUT + nt * 16 + n] = acc[t2][nt][r];
      }
    }
  }
}

// ---------- K5: out = (sum_js opart)/(sum_js Dpart) + bias ----------
__global__ void k_final_part(float* __restrict__ out, const float* __restrict__ opart,
                             const float* __restrict__ Dpart, const float* __restrict__ bias) {
  int i = blockIdx.x;
  int c = threadIdx.x;
  float s = 0.f, d = 0.f;
#pragma unroll
  for (int js = 0; js < 8; ++js) {
    s += opart[((size_t)js * NN + i) * COUT + c];
    d += Dpart[(size_t)js * NN + i];
  }
  out[(size_t)i * COUT + c] = s / fmaxf(d, 1e-37f) + bias[c];
}

// ---------- Fallback path (atomics, direct adj) if ws is too small ----------
__global__ __launch_bounds__(256, 2)
void k_attn_atomic(const int* __restrict__ adj, const unsigned short* __restrict__ ht,
                   const float* __restrict__ e1, const float* __restrict__ e2,
                   float* __restrict__ out_num, float* __restrict__ Dbuf) {
  int b = blockIdx.x;
  int rg = b >> 3, js = b & 7;
  int wave = threadIdx.x >> 6, lane = threadIdx.x & 63;
  int n = lane & 15, q = lane >> 4;
  int rowbase = rg * 128 + wave * 32;

  float e1v0 = e1[rowbase + n];
  float e1v1 = e1[rowbase + 16 + n];

  floatx4 acc[2][16];
#pragma unroll
  for (int t = 0; t < 2; ++t)
#pragma unroll
    for (int nt = 0; nt < 16; ++nt) acc[t][nt] = (floatx4){0.f, 0.f, 0.f, 0.f};

  float d0 = 0.f, d1 = 0.f;
  int jbeg = js * 1024;

  for (int ch = 0; ch < 32; ++ch) {
    int j0 = jbeg + ch * 32 + q * 8;
    floatx4 ea = *(const floatx4*)(e2 + j0);
    floatx4 eb = *(const floatx4*)(e2 + j0 + 4);
    float ev[8] = {ea.x, ea.y, ea.z, ea.w, eb.x, eb.y, eb.z, eb.w};

    intx4 A00 = *(const intx4*)(adj + (size_t)(rowbase + n) * NN + j0);
    intx4 A01 = *(const intx4*)(adj + (size_t)(rowbase + n) * NN + j0 + 4);
    intx4 A10 = *(const intx4*)(adj + (size_t)(rowbase + 16 + n) * NN + j0);
    intx4 A11 = *(const intx4*)(adj + (size_t)(rowbase + 16 + n) * NN + j0 + 4);

    float p0[8], p1[8];
#pragma unroll
    for (int jj = 0; jj < 8; ++jj) {
      int av0 = (jj < 4) ? A00[jj] : A01[jj - 4];
      int av1 = (jj < 4) ? A10[jj] : A11[jj - 4];
      float t0 = e1v0 + ev[jj];
      float t1 = e1v1 + ev[jj];
      float f0 = fmaxf(t0, 0.25f * t0);
      float f1 = fmaxf(t1, 0.25f * t1);
      float x0 = __expf(f0 - SHIFT);
      float x1 = __expf(f1 - SHIFT);
      p0[jj] = (av0 != 0) ? x0 : 0.f;
      p1[jj] = (av1 != 0) ? x1 : 0.f;
      d0 += p0[jj];
      d1 += p1[jj];
    }
    short8 af0 = pack8(p0);
    short8 af1 = pack8(p1);

#pragma unroll
    for (int g = 0; g < 2; ++g) {
      short8 bf[8];
#pragma unroll
      for (int t = 0; t < 8; ++t)
        bf[t] = *(const short8*)(ht + (size_t)((g * 8 + t) * 16 + n) * NN + j0);
#pragma unroll
      for (int t = 0; t < 8; ++t) {
        acc[0][g * 8 + t] = __builtin_amdgcn_mfma_f32_16x16x32_bf16(af0, bf[t], acc[0][g * 8 + t], 0, 0, 0);
        acc[1][g * 8 + t] = __builtin_amdgcn_mfma_f32_16x16x32_bf16(af1, bf[t], acc[1][g * 8 + t], 0, 0, 0);
      }
    }
  }

  d0 += __shfl_xor(d0, 16); d0 += __shfl_xor(d0, 32);
  d1 += __shfl_xor(d1, 16); d1 += __shfl_xor(d1, 32);
  if (lane < 16) {
    atomicAdd(Dbuf + rowbase + lane, d0);
    atomicAdd(Dbuf + rowbase + 16 + lane, d1);
  }

#pragma unroll
  for (int t2 = 0; t2 < 2; ++t2) {
#pragma unroll
    for (int nt = 0; nt < 16; ++nt) {
#pragma unroll
      for (int r = 0; r < 4; ++r) {
        int i = rowbase + t2 * 16 + q * 4 + r;
        atomicAdd(out_num + (size_t)i * COUT + nt * 16 + n, acc[t2][nt][r]);
      }
    }
  }
}

__global__ void k_final_atomic(float* __restrict__ out, const float* __restrict__ Dbuf,
                               const float* __restrict__ bias) {
  int idx = blockIdx.x * 256 + threadIdx.x;
  int i = idx >> 8, c = idx & 255;
  float d = fmaxf(Dbuf[i], 1e-37f);
  out[idx] = out[idx] / d + bias[c];
}

// ---------- launch ----------
extern "C" void kernel_launch(void* const* d_in, const int* in_sizes, int n_in,
                              void* d_out, int out_size, void* d_ws, size_t ws_size,
                              hipStream_t stream) {
  const float* input   = (const float*)d_in[0];
  const int*   adj     = (const int*)d_in[1];
  const float* weights = (const float*)d_in[2];
  const float* a1      = (const float*)d_in[3];
  const float* a2      = (const float*)d_in[4];
  const float* bias    = (const float*)d_in[5];
  float* out = (float*)d_out;
  char* ws = (char*)d_ws;

  // ws layout
  unsigned short* inA = (unsigned short*)(ws);                 // 8 MB   [8192][512] bf16
  unsigned short* wt  = (unsigned short*)(ws + 8388608);       // 256 KB [256][512] bf16
  unsigned short* ht  = (unsigned short*)(ws + 8650752);       // 4 MB   [256][8192] bf16
  float* e1    = (float*)(ws + 12845056);                      // 32 KB
  float* e2    = (float*)(ws + 12877824);                      // 32 KB
  float* Dpart = (float*)(ws + 12910592);                      // 256 KB [8][8192]
  unsigned int* bm = (unsigned int*)(ws + 13172736);           // 8 MB   [8192][256] u32
  float* opart = (float*)(ws + 21561344);                      // 64 MB  [8][8192][256]
  const size_t WS_NEEDED_PART = 21561344 + (size_t)8 * NN * COUT * 4;  // ~85 MB
  float* Dbuf = Dpart;                                         // fallback reuse

  if (ws_size >= WS_NEEDED_PART) {
    k_compress<<<8192, 256, 0, stream>>>(adj, bm);
    k_cast_input<<<4096, 256, 0, stream>>>(input, (ushortx4*)inA);
    k_prep_w<<<512, 256, 0, stream>>>(weights, wt);
    k_gemm_h<<<128, 256, 0, stream>>>(inA, wt, a1, a2, ht, e1, e2);
    k_attn_part<<<512, 256, 0, stream>>>(bm, ht, e1, e2, opart, Dpart);
    k_final_part<<<8192, 256, 0, stream>>>(out, opart, Dpart, bias);
  } else {
    k_cast_input<<<4096, 256, 0, stream>>>(input, (ushortx4*)inA);
    k_prep_w<<<512, 256, 0, stream>>>(weights, wt);
    k_gemm_h<<<128, 256, 0, stream>>>(inA, wt, a1, a2, ht, e1, e2);
    hipMemsetAsync(out, 0, (size_t)NN * COUT * sizeof(float), stream);
    hipMemsetAsync(Dbuf, 0, NN * sizeof(float), stream);
    k_attn_atomic<<<512, 256, 0, stream>>>(adj, ht, e1, e2, out, Dbuf);
    k_final_atomic<<<8192, 256, 0, stream>>>(out, Dbuf, bias);
  }
}

// Round 4
// 487.645 us; speedup vs baseline: 1.1633x; 1.1633x over previous
//
#include <hip/hip_runtime.h>

typedef __attribute__((ext_vector_type(8))) short short8;
typedef __attribute__((ext_vector_type(4))) float floatx4;
typedef __attribute__((ext_vector_type(4))) unsigned int uintx4;
typedef __attribute__((ext_vector_type(2))) unsigned int uintx2;
typedef __attribute__((ext_vector_type(4))) int intx4;
typedef __attribute__((ext_vector_type(4))) unsigned short ushortx4;
typedef unsigned int u32;

#define NN 8192
#define KIN 512
#define COUT 256
#define SHIFT 16.0f

#define AS1 __attribute__((address_space(1)))
#define AS3 __attribute__((address_space(3)))

// async global->LDS, 16B per lane; lds ptr must be wave-uniform (lane*16 auto)
__device__ __forceinline__ void stage16(const void* g, void* l) {
  __builtin_amdgcn_global_load_lds((const AS1 u32*)g, (AS3 u32*)l, 16, 0, 0);
}

// ---------- helpers ----------
__device__ __forceinline__ unsigned int f2bf(float f) {
  unsigned int u = __float_as_uint(f);
  return (u + 0x7FFFu + ((u >> 16) & 1u)) >> 16;  // RNE round to bf16
}

__device__ __forceinline__ short8 pack8(const float* p) {
  uintx4 w;
  w.x = f2bf(p[0]) | (f2bf(p[1]) << 16);
  w.y = f2bf(p[2]) | (f2bf(p[3]) << 16);
  w.z = f2bf(p[4]) | (f2bf(p[5]) << 16);
  w.w = f2bf(p[6]) | (f2bf(p[7]) << 16);
  union { uintx4 u; short8 s; } cv; cv.u = w;
  return cv.s;
}

// ---------- K0: compress adj int32 -> row-major bitmask bm[8192][256] u32 ----------
__global__ __launch_bounds__(256)
void k_compress(const int* __restrict__ adj, unsigned int* __restrict__ bm) {
  int idx = blockIdx.x * 256 + threadIdx.x;          // 2M words
  const int* p = adj + (size_t)idx * 32;
  unsigned int m = 0;
#pragma unroll
  for (int k = 0; k < 8; ++k) {
    intx4 v = *(const intx4*)(p + k * 4);
    m |= (v.x != 0 ? 1u : 0u) << (k * 4 + 0);
    m |= (v.y != 0 ? 1u : 0u) << (k * 4 + 1);
    m |= (v.z != 0 ? 1u : 0u) << (k * 4 + 2);
    m |= (v.w != 0 ? 1u : 0u) << (k * 4 + 3);
  }
  bm[idx] = m;
}

// ---------- K1a: cast input fp32 -> bf16 ----------
__global__ void k_cast_input(const float* __restrict__ in, ushortx4* __restrict__ out) {
  int idx = blockIdx.x * 256 + threadIdx.x;
  floatx4 v = ((const floatx4*)in)[idx];
  ushortx4 o;
  o.x = (unsigned short)f2bf(v.x);
  o.y = (unsigned short)f2bf(v.y);
  o.z = (unsigned short)f2bf(v.z);
  o.w = (unsigned short)f2bf(v.w);
  out[idx] = o;
}

// ---------- K1b: weights [512][256] fp32 -> wt [256][512] bf16 (transposed) ----------
__global__ void k_prep_w(const float* __restrict__ w, unsigned short* __restrict__ wt) {
  int idx = blockIdx.x * 256 + threadIdx.x;
  int k = idx >> 8, c = idx & 255;
  wt[c * KIN + k] = (unsigned short)f2bf(w[idx]);
}

// ---------- K2: h = X*W via MFMA; emit ht[256][8192] bf16, e1[8192], e2[8192] ----------
__global__ __launch_bounds__(256)
void k_gemm_h(const unsigned short* __restrict__ inA, const unsigned short* __restrict__ wt,
              const float* __restrict__ a1, const float* __restrict__ a2,
              unsigned short* __restrict__ ht, float* __restrict__ e1, float* __restrict__ e2) {
  int wave = threadIdx.x >> 6;
  int lane = threadIdx.x & 63;
  int n = lane & 15, q = lane >> 4;
  int row0 = blockIdx.x * 64 + wave * 16;
  int mrow = row0 + n;

  floatx4 acc[16];
#pragma unroll
  for (int t = 0; t < 16; ++t) acc[t] = (floatx4){0.f, 0.f, 0.f, 0.f};

  for (int kc = 0; kc < KIN / 32; ++kc) {
    int k0 = kc * 32 + q * 8;
    short8 a = *(const short8*)(inA + (size_t)mrow * KIN + k0);
#pragma unroll
    for (int nt = 0; nt < 16; ++nt) {
      short8 b = *(const short8*)(wt + (size_t)(nt * 16 + n) * KIN + k0);
      acc[nt] = __builtin_amdgcn_mfma_f32_16x16x32_bf16(a, b, acc[nt], 0, 0, 0);
    }
  }

  int i0 = row0 + q * 4;
#pragma unroll
  for (int nt = 0; nt < 16; ++nt) {
    int c = nt * 16 + n;
    uintx2 pk;
    pk.x = f2bf(acc[nt][0]) | (f2bf(acc[nt][1]) << 16);
    pk.y = f2bf(acc[nt][2]) | (f2bf(acc[nt][3]) << 16);
    *(uintx2*)(ht + (size_t)c * NN + i0) = pk;
  }

  float s1[4] = {0.f, 0.f, 0.f, 0.f}, s2[4] = {0.f, 0.f, 0.f, 0.f};
#pragma unroll
  for (int nt = 0; nt < 16; ++nt) {
    float w1 = a1[nt * 16 + n];
    float w2 = a2[nt * 16 + n];
#pragma unroll
    for (int r = 0; r < 4; ++r) {
      s1[r] += acc[nt][r] * w1;
      s2[r] += acc[nt][r] * w2;
    }
  }
#pragma unroll
  for (int m = 1; m < 16; m <<= 1) {
#pragma unroll
    for (int r = 0; r < 4; ++r) {
      s1[r] += __shfl_xor(s1[r], m);
      s2[r] += __shfl_xor(s2[r], m);
    }
  }
  if (n == 0) {
#pragma unroll
    for (int r = 0; r < 4; ++r) {
      e1[i0 + r] = s1[r];
      e2[i0 + r] = s2[r];
    }
  }
}

// ---------- K4: masked-softmax attention + PV, bitmask adj, LDS-staged ht ----------
// grid = 64 rowgroups x 8 j-slices = 512 blocks; wave = 32 rows x 256 cols.
// ht chunk-tile (256 ch x 32 j = 16 KB) staged ONCE per block via global_load_lds,
// double-buffered; all 4 waves ds_read it (replaces 4x redundant per-wave L1/L2 pulls).
__global__ __launch_bounds__(256, 2)
void k_attn_part(const unsigned int* __restrict__ bm, const unsigned short* __restrict__ ht,
                 const float* __restrict__ e1, const float* __restrict__ e2,
                 float* __restrict__ opart, float* __restrict__ Dpart) {
  __shared__ __align__(16) char smem[32768];         // 2 x 16 KB ht tiles

  int b = blockIdx.x;
  int rg = b >> 3, js = b & 7;
  int wave = threadIdx.x >> 6, lane = threadIdx.x & 63;
  int n = lane & 15, q = lane >> 4;
  int rowbase = rg * 128 + wave * 32;
  int jbeg = js * 1024;

  float e1v0 = e1[rowbase + n];
  float e1v1 = e1[rowbase + 16 + n];

  const unsigned int* bp0 = bm + (size_t)(rowbase + n) * 256 + js * 32;
  const unsigned int* bp1 = bm + (size_t)(rowbase + 16 + n) * 256 + js * 32;

  floatx4 acc[2][16];
#pragma unroll
  for (int t = 0; t < 2; ++t)
#pragma unroll
    for (int nt = 0; nt < 16; ++nt) acc[t][nt] = (floatx4){0.f, 0.f, 0.f, 0.f};

  float d0 = 0.f, d1 = 0.f;

  // stage chunk ch's ht tile into buf: LDS layout seg = c*4 + (jcol/8), 16 B/seg
  // wave-uniform lds base (wave*256 + i*64)*16; lane l lands at +l*16 = seg l's slot.
  auto stage = [&](int ch, int buf) {
    int j0g = jbeg + ch * 32;
    int segbase = wave * 256;
#pragma unroll
    for (int i = 0; i < 4; ++i) {
      int seg = segbase + i * 64 + lane;
      int c = seg >> 2;
      int js8 = (seg & 3) * 8;
      stage16(ht + (size_t)c * NN + j0g + js8,
              smem + (size_t)buf * 16384 + (size_t)(segbase + i * 64) * 16);
    }
  };

  stage(0, 0);
  __syncthreads();                                   // chunk 0 tile ready

  for (int ch = 0; ch < 32; ++ch) {
    int cur = ch & 1;
    if (ch < 31) stage(ch + 1, cur ^ 1);             // prefetch next tile (drained at barrier)

    int j0 = jbeg + ch * 32 + q * 8;
    floatx4 ea = *(const floatx4*)(e2 + j0);
    floatx4 eb = *(const floatx4*)(e2 + j0 + 4);
    float ev[8] = {ea.x, ea.y, ea.z, ea.w, eb.x, eb.y, eb.z, eb.w};

    unsigned int by0 = (bp0[ch] >> (q * 8)) & 0xffu;
    unsigned int by1 = (bp1[ch] >> (q * 8)) & 0xffu;

    float p0[8], p1[8];
#pragma unroll
    for (int jj = 0; jj < 8; ++jj) {
      float t0 = e1v0 + ev[jj];
      float t1 = e1v1 + ev[jj];
      float f0 = fmaxf(t0, 0.25f * t0);              // leakyrelu
      float f1 = fmaxf(t1, 0.25f * t1);
      float x0 = __expf(f0 - SHIFT);                 // fixed shift: exp <= ~0.14 always
      float x1 = __expf(f1 - SHIFT);
      p0[jj] = ((by0 >> jj) & 1u) ? x0 : 0.f;
      p1[jj] = ((by1 >> jj) & 1u) ? x1 : 0.f;
      d0 += p0[jj];
      d1 += p1[jj];
    }
    short8 af0 = pack8(p0);
    short8 af1 = pack8(p1);

    // B-frags from LDS: frag(t,n,q) at byte t*1024 + n*64 + q*16
    const short8* lb = (const short8*)(smem + (size_t)cur * 16384);
#pragma unroll
    for (int t = 0; t < 16; ++t) {
      short8 bf = lb[t * 64 + n * 4 + q];
      acc[0][t] = __builtin_amdgcn_mfma_f32_16x16x32_bf16(af0, bf, acc[0][t], 0, 0, 0);
      acc[1][t] = __builtin_amdgcn_mfma_f32_16x16x32_bf16(af1, bf, acc[1][t], 0, 0, 0);
    }

    __syncthreads();                                 // drain stage(ch+1), protect buffers
  }

  d0 += __shfl_xor(d0, 16); d0 += __shfl_xor(d0, 32);
  d1 += __shfl_xor(d1, 16); d1 += __shfl_xor(d1, 32);
  if (lane < 16) {
    Dpart[(size_t)js * NN + rowbase + lane] = d0;
    Dpart[(size_t)js * NN + rowbase + 16 + lane] = d1;
  }

  float* op = opart + (size_t)js * NN * COUT;
#pragma unroll
  for (int t2 = 0; t2 < 2; ++t2) {
#pragma unroll
    for (int nt = 0; nt < 16; ++nt) {
#pragma unroll
      for (int r = 0; r < 4; ++r) {
        int i = rowbase + t2 * 16 + q * 4 + r;
        op[(size_t)i * COUT + nt * 16 + n] = acc[t2][nt][r];
      }
    }
  }
}

// ---------- K5: out = (sum_js opart)/(sum_js Dpart) + bias ----------
__global__ void k_final_part(float* __restrict__ out, const float* __restrict__ opart,
                             const float* __restrict__ Dpart, const float* __restrict__ bias) {
  int i = blockIdx.x;
  int c = threadIdx.x;
  float s = 0.f, d = 0.f;
#pragma unroll
  for (int js = 0; js < 8; ++js) {
    s += opart[((size_t)js * NN + i) * COUT + c];
    d += Dpart[(size_t)js * NN + i];
  }
  out[(size_t)i * COUT + c] = s / fmaxf(d, 1e-37f) + bias[c];
}

// ---------- Fallback path (atomics, direct adj) if ws is too small ----------
__global__ __launch_bounds__(256, 2)
void k_attn_atomic(const int* __restrict__ adj, const unsigned short* __restrict__ ht,
                   const float* __restrict__ e1, const float* __restrict__ e2,
                   float* __restrict__ out_num, float* __restrict__ Dbuf) {
  int b = blockIdx.x;
  int rg = b >> 3, js = b & 7;
  int wave = threadIdx.x >> 6, lane = threadIdx.x & 63;
  int n = lane & 15, q = lane >> 4;
  int rowbase = rg * 128 + wave * 32;

  float e1v0 = e1[rowbase + n];
  float e1v1 = e1[rowbase + 16 + n];

  floatx4 acc[2][16];
#pragma unroll
  for (int t = 0; t < 2; ++t)
#pragma unroll
    for (int nt = 0; nt < 16; ++nt) acc[t][nt] = (floatx4){0.f, 0.f, 0.f, 0.f};

  float d0 = 0.f, d1 = 0.f;
  int jbeg = js * 1024;

  for (int ch = 0; ch < 32; ++ch) {
    int j0 = jbeg + ch * 32 + q * 8;
    floatx4 ea = *(const floatx4*)(e2 + j0);
    floatx4 eb = *(const floatx4*)(e2 + j0 + 4);
    float ev[8] = {ea.x, ea.y, ea.z, ea.w, eb.x, eb.y, eb.z, eb.w};

    intx4 A00 = *(const intx4*)(adj + (size_t)(rowbase + n) * NN + j0);
    intx4 A01 = *(const intx4*)(adj + (size_t)(rowbase + n) * NN + j0 + 4);
    intx4 A10 = *(const intx4*)(adj + (size_t)(rowbase + 16 + n) * NN + j0);
    intx4 A11 = *(const intx4*)(adj + (size_t)(rowbase + 16 + n) * NN + j0 + 4);

    float p0[8], p1[8];
#pragma unroll
    for (int jj = 0; jj < 8; ++jj) {
      int av0 = (jj < 4) ? A00[jj] : A01[jj - 4];
      int av1 = (jj < 4) ? A10[jj] : A11[jj - 4];
      float t0 = e1v0 + ev[jj];
      float t1 = e1v1 + ev[jj];
      float f0 = fmaxf(t0, 0.25f * t0);
      float f1 = fmaxf(t1, 0.25f * t1);
      float x0 = __expf(f0 - SHIFT);
      float x1 = __expf(f1 - SHIFT);
      p0[jj] = (av0 != 0) ? x0 : 0.f;
      p1[jj] = (av1 != 0) ? x1 : 0.f;
      d0 += p0[jj];
      d1 += p1[jj];
    }
    short8 af0 = pack8(p0);
    short8 af1 = pack8(p1);

#pragma unroll
    for (int g = 0; g < 2; ++g) {
      short8 bf[8];
#pragma unroll
      for (int t = 0; t < 8; ++t)
        bf[t] = *(const short8*)(ht + (size_t)((g * 8 + t) * 16 + n) * NN + j0);
#pragma unroll
      for (int t = 0; t < 8; ++t) {
        acc[0][g * 8 + t] = __builtin_amdgcn_mfma_f32_16x16x32_bf16(af0, bf[t], acc[0][g * 8 + t], 0, 0, 0);
        acc[1][g * 8 + t] = __builtin_amdgcn_mfma_f32_16x16x32_bf16(af1, bf[t], acc[1][g * 8 + t], 0, 0, 0);
      }
    }
  }

  d0 += __shfl_xor(d0, 16); d0 += __shfl_xor(d0, 32);
  d1 += __shfl_xor(d1, 16); d1 += __shfl_xor(d1, 32);
  if (lane < 16) {
    atomicAdd(Dbuf + rowbase + lane, d0);
    atomicAdd(Dbuf + rowbase + 16 + lane, d1);
  }

#pragma unroll
  for (int t2 = 0; t2 < 2; ++t2) {
#pragma unroll
    for (int nt = 0; nt < 16; ++nt) {
#pragma unroll
      for (int r = 0; r < 4; ++r) {
        int i = rowbase + t2 * 16 + q * 4 + r;
        atomicAdd(out_num + (size_t)i * COUT + nt * 16 + n, acc[t2][nt][r]);
      }
    }
  }
}

__global__ void k_final_atomic(float* __restrict__ out, const float* __restrict__ Dbuf,
                               const float* __restrict__ bias) {
  int idx = blockIdx.x * 256 + threadIdx.x;
  int i = idx >> 8, c = idx & 255;
  float d = fmaxf(Dbuf[i], 1e-37f);
  out[idx] = out[idx] / d + bias[c];
}

// ---------- launch ----------
extern "C" void kernel_launch(void* const* d_in, const int* in_sizes, int n_in,
                              void* d_out, int out_size, void* d_ws, size_t ws_size,
                              hipStream_t stream) {
  const float* input   = (const float*)d_in[0];
  const int*   adj     = (const int*)d_in[1];
  const float* weights = (const float*)d_in[2];
  const float* a1      = (const float*)d_in[3];
  const float* a2      = (const float*)d_in[4];
  const float* bias    = (const float*)d_in[5];
  float* out = (float*)d_out;
  char* ws = (char*)d_ws;

  unsigned short* inA = (unsigned short*)(ws);                 // 8 MB
  unsigned short* wt  = (unsigned short*)(ws + 8388608);       // 256 KB
  unsigned short* ht  = (unsigned short*)(ws + 8650752);       // 4 MB
  float* e1    = (float*)(ws + 12845056);                      // 32 KB
  float* e2    = (float*)(ws + 12877824);                      // 32 KB
  float* Dpart = (float*)(ws + 12910592);                      // 256 KB [8][8192]
  unsigned int* bm = (unsigned int*)(ws + 13172736);           // 8 MB
  float* opart = (float*)(ws + 21561344);                      // 64 MB [8][8192][256]
  const size_t WS_NEEDED_PART = 21561344 + (size_t)8 * NN * COUT * 4;  // ~85 MB
  float* Dbuf = Dpart;

  if (ws_size >= WS_NEEDED_PART) {
    k_compress<<<8192, 256, 0, stream>>>(adj, bm);
    k_cast_input<<<4096, 256, 0, stream>>>(input, (ushortx4*)inA);
    k_prep_w<<<512, 256, 0, stream>>>(weights, wt);
    k_gemm_h<<<128, 256, 0, stream>>>(inA, wt, a1, a2, ht, e1, e2);
    k_attn_part<<<512, 256, 0, stream>>>(bm, ht, e1, e2, opart, Dpart);
    k_final_part<<<8192, 256, 0, stream>>>(out, opart, Dpart, bias);
  } else {
    k_cast_input<<<4096, 256, 0, stream>>>(input, (ushortx4*)inA);
    k_prep_w<<<512, 256, 0, stream>>>(weights, wt);
    k_gemm_h<<<128, 256, 0, stream>>>(inA, wt, a1, a2, ht, e1, e2);
    hipMemsetAsync(out, 0, (size_t)NN * COUT * sizeof(float), stream);
    hipMemsetAsync(Dbuf, 0, NN * sizeof(float), stream);
    k_attn_atomic<<<512, 256, 0, stream>>>(adj, ht, e1, e2, out, Dbuf);
    k_final_atomic<<<8192, 256, 0, stream>>>(out, Dbuf, bias);
  }
}

// Round 5
// 463.679 us; speedup vs baseline: 1.2234x; 1.0517x over previous
//
#include <hip/hip_runtime.h>

typedef __attribute__((ext_vector_type(8))) short short8;
typedef __attribute__((ext_vector_type(4))) float floatx4;
typedef __attribute__((ext_vector_type(4))) unsigned int uintx4;
typedef __attribute__((ext_vector_type(2))) unsigned int uintx2;
typedef __attribute__((ext_vector_type(4))) int intx4;
typedef __attribute__((ext_vector_type(4))) unsigned short ushortx4;
typedef unsigned int u32;

#define NN 8192
#define KIN 512
#define COUT 256
#define SHIFT 16.0f

#define AS1 __attribute__((address_space(1)))
#define AS3 __attribute__((address_space(3)))

// async global->LDS, 16B per lane; LDS base wave-uniform, lane lands at +lane*16
__device__ __forceinline__ void stage16(const void* g, void* l) {
  __builtin_amdgcn_global_load_lds((const AS1 u32*)g, (AS3 u32*)l, 16, 0, 0);
}

// ---------- helpers ----------
__device__ __forceinline__ unsigned int f2bf(float f) {
  unsigned int u = __float_as_uint(f);
  return (u + 0x7FFFu + ((u >> 16) & 1u)) >> 16;  // RNE round to bf16
}

__device__ __forceinline__ short8 pack8(const float* p) {
  uintx4 w;
  w.x = f2bf(p[0]) | (f2bf(p[1]) << 16);
  w.y = f2bf(p[2]) | (f2bf(p[3]) << 16);
  w.z = f2bf(p[4]) | (f2bf(p[5]) << 16);
  w.w = f2bf(p[6]) | (f2bf(p[7]) << 16);
  union { uintx4 u; short8 s; } cv; cv.u = w;
  return cv.s;
}

// ---------- K1a: cast input fp32 -> bf16 ----------
__global__ void k_cast_input(const float* __restrict__ in, ushortx4* __restrict__ out) {
  int idx = blockIdx.x * 256 + threadIdx.x;
  floatx4 v = ((const floatx4*)in)[idx];
  ushortx4 o;
  o.x = (unsigned short)f2bf(v.x);
  o.y = (unsigned short)f2bf(v.y);
  o.z = (unsigned short)f2bf(v.z);
  o.w = (unsigned short)f2bf(v.w);
  out[idx] = o;
}

// ---------- K1b: weights [512][256] fp32 -> wt [256][512] bf16 (transposed) ----------
__global__ void k_prep_w(const float* __restrict__ w, unsigned short* __restrict__ wt) {
  int idx = blockIdx.x * 256 + threadIdx.x;
  int k = idx >> 8, c = idx & 255;
  wt[c * KIN + k] = (unsigned short)f2bf(w[idx]);
}

// ---------- K2: h = X*W via MFMA; emit ht[256][8192] bf16, e1[8192], e2[8192] ----------
__global__ __launch_bounds__(256)
void k_gemm_h(const unsigned short* __restrict__ inA, const unsigned short* __restrict__ wt,
              const float* __restrict__ a1, const float* __restrict__ a2,
              unsigned short* __restrict__ ht, float* __restrict__ e1, float* __restrict__ e2) {
  int wave = threadIdx.x >> 6;
  int lane = threadIdx.x & 63;
  int n = lane & 15, q = lane >> 4;
  int row0 = blockIdx.x * 64 + wave * 16;
  int mrow = row0 + n;

  floatx4 acc[16];
#pragma unroll
  for (int t = 0; t < 16; ++t) acc[t] = (floatx4){0.f, 0.f, 0.f, 0.f};

  for (int kc = 0; kc < KIN / 32; ++kc) {
    int k0 = kc * 32 + q * 8;
    short8 a = *(const short8*)(inA + (size_t)mrow * KIN + k0);
#pragma unroll
    for (int nt = 0; nt < 16; ++nt) {
      short8 b = *(const short8*)(wt + (size_t)(nt * 16 + n) * KIN + k0);
      acc[nt] = __builtin_amdgcn_mfma_f32_16x16x32_bf16(a, b, acc[nt], 0, 0, 0);
    }
  }

  int i0 = row0 + q * 4;
#pragma unroll
  for (int nt = 0; nt < 16; ++nt) {
    int c = nt * 16 + n;
    uintx2 pk;
    pk.x = f2bf(acc[nt][0]) | (f2bf(acc[nt][1]) << 16);
    pk.y = f2bf(acc[nt][2]) | (f2bf(acc[nt][3]) << 16);
    *(uintx2*)(ht + (size_t)c * NN + i0) = pk;
  }

  float s1[4] = {0.f, 0.f, 0.f, 0.f}, s2[4] = {0.f, 0.f, 0.f, 0.f};
#pragma unroll
  for (int nt = 0; nt < 16; ++nt) {
    float w1 = a1[nt * 16 + n];
    float w2 = a2[nt * 16 + n];
#pragma unroll
    for (int r = 0; r < 4; ++r) {
      s1[r] += acc[nt][r] * w1;
      s2[r] += acc[nt][r] * w2;
    }
  }
#pragma unroll
  for (int m = 1; m < 16; m <<= 1) {
#pragma unroll
    for (int r = 0; r < 4; ++r) {
      s1[r] += __shfl_xor(s1[r], m);
      s2[r] += __shfl_xor(s2[r], m);
    }
  }
  if (n == 0) {
#pragma unroll
    for (int r = 0; r < 4; ++r) {
      e1[i0 + r] = s1[r];
      e2[i0 + r] = s2[r];
    }
  }
}

// ---------- K4: FUSED masked-softmax attention + PV, adj streamed direct-to-LDS ----------
// grid = 64 rowgroups x 8 j-slices = 512 blocks; wave = 32 rows x 256 cols.
// Per chunk (32 cols): ht tile 16 KB (L2) + adj tile 16 KB (HBM, consumed once)
// staged via global_load_lds, double-buffered. No separate compress pass, no bm.
__global__ __launch_bounds__(256, 2)
void k_attn_fused(const int* __restrict__ adj, const unsigned short* __restrict__ ht,
                  const float* __restrict__ e1, const float* __restrict__ e2,
                  float* __restrict__ opart, float* __restrict__ Dpart) {
  // LDS: buf0 [ht 16K | adj 16K] buf1 [ht 16K | adj 16K] e2s 4K = 69632 B
  __shared__ __align__(16) char smem[69632];
  float* e2s = (float*)(smem + 65536);

  int b = blockIdx.x;
  int rg = b >> 3, js = b & 7;                       // js = b&7: slice per XCD (L2 locality)
  int wave = threadIdx.x >> 6, lane = threadIdx.x & 63;
  int n = lane & 15, q = lane >> 4;
  int rowblock = rg * 128;
  int rowbase = rowblock + wave * 32;
  int jbeg = js * 1024;

  // e2 slice -> LDS once (kills per-chunk dependent L2 load)
  ((floatx4*)e2s)[threadIdx.x] = *(const floatx4*)(e2 + jbeg + threadIdx.x * 4);

  float e1v0 = e1[rowbase + n];
  float e1v1 = e1[rowbase + 16 + n];

  floatx4 acc[2][16];
#pragma unroll
  for (int t = 0; t < 2; ++t)
#pragma unroll
    for (int nt = 0; nt < 16; ++nt) acc[t][nt] = (floatx4){0.f, 0.f, 0.f, 0.f};

  float d0 = 0.f, d1 = 0.f;

  // stage chunk ch into buf.
  // ht tile: 1024 segs of 16 B, seg = c*4 + (jcol/8); wave covers segs [wave*256, +256).
  // adj tile: wave stages its OWN 32 rows; issue i: lane l -> row i*8+(l&7), colgroup l>>3.
  //   LDS holds [issue][cg][row&7] so mask ds_reads spread across all 32 banks.
  auto stage = [&](int ch, int buf) {
    int j0g = jbeg + ch * 32;
    char* hbase = smem + buf * 32768;
#pragma unroll
    for (int i = 0; i < 4; ++i) {
      int seg = wave * 256 + i * 64 + lane;
      int c = seg >> 2;
      int j8 = (seg & 3) * 8;
      stage16(ht + (size_t)c * NN + j0g + j8, hbase + (size_t)(wave * 256 + i * 64) * 16);
    }
    char* abase = hbase + 16384 + wave * 4096;
    const int* aw = adj + (size_t)(rowblock + wave * 32) * NN + j0g;
#pragma unroll
    for (int i = 0; i < 4; ++i) {
      stage16(aw + (size_t)(i * 8 + (lane & 7)) * NN + (lane >> 3) * 4, abase + i * 1024);
    }
  };

  stage(0, 0);
  __syncthreads();                                   // chunk 0 tiles ready

  int rlo = n & 7, rhi = n >> 3;

  for (int ch = 0; ch < 32; ++ch) {
    int cur = ch & 1;
    if (ch < 31) stage(ch + 1, cur ^ 1);             // prefetch next (drains at barrier)

    // adj masks from LDS: row n at rhi*1024 + q*256 + rlo*16 (+128 for cols +4; +2048 for row n+16)
    const char* ab = smem + cur * 32768 + 16384 + wave * 4096;
    intx4 a0a = *(const intx4*)(ab + rhi * 1024 + q * 256 + rlo * 16);
    intx4 a0b = *(const intx4*)(ab + rhi * 1024 + q * 256 + 128 + rlo * 16);
    intx4 a1a = *(const intx4*)(ab + 2048 + rhi * 1024 + q * 256 + rlo * 16);
    intx4 a1b = *(const intx4*)(ab + 2048 + rhi * 1024 + q * 256 + 128 + rlo * 16);

    floatx4 ea = *(const floatx4*)(e2s + ch * 32 + q * 8);
    floatx4 eb = *(const floatx4*)(e2s + ch * 32 + q * 8 + 4);
    float ev[8] = {ea.x, ea.y, ea.z, ea.w, eb.x, eb.y, eb.z, eb.w};

    float p0[8], p1[8];
#pragma unroll
    for (int jj = 0; jj < 8; ++jj) {
      int av0 = (jj < 4) ? a0a[jj] : a0b[jj - 4];
      int av1 = (jj < 4) ? a1a[jj] : a1b[jj - 4];
      float t0 = e1v0 + ev[jj];
      float t1 = e1v1 + ev[jj];
      float f0 = fmaxf(t0, 0.25f * t0);              // leakyrelu (slope 0.25)
      float f1 = fmaxf(t1, 0.25f * t1);
      float x0 = __expf(f0 - SHIFT);                 // fixed shift: exp <= ~0.14 always
      float x1 = __expf(f1 - SHIFT);
      p0[jj] = (av0 != 0) ? x0 : 0.f;
      p1[jj] = (av1 != 0) ? x1 : 0.f;
      d0 += p0[jj];
      d1 += p1[jj];
    }
    short8 af0 = pack8(p0);
    short8 af1 = pack8(p1);

    // B-frags from LDS ht tile: frag(t,n,q) at byte t*1024 + n*64 + q*16
    const short8* lb = (const short8*)(smem + (size_t)cur * 32768);
#pragma unroll
    for (int t = 0; t < 16; ++t) {
      short8 bf = lb[t * 64 + n * 4 + q];
      acc[0][t] = __builtin_amdgcn_mfma_f32_16x16x32_bf16(af0, bf, acc[0][t], 0, 0, 0);
      acc[1][t] = __builtin_amdgcn_mfma_f32_16x16x32_bf16(af1, bf, acc[1][t], 0, 0, 0);
    }

    __syncthreads();                                 // drain stage(ch+1), protect buffers
  }

  d0 += __shfl_xor(d0, 16); d0 += __shfl_xor(d0, 32);
  d1 += __shfl_xor(d1, 16); d1 += __shfl_xor(d1, 32);
  if (lane < 16) {
    Dpart[(size_t)js * NN + rowbase + lane] = d0;
    Dpart[(size_t)js * NN + rowbase + 16 + lane] = d1;
  }

  float* op = opart + (size_t)js * NN * COUT;
#pragma unroll
  for (int t2 = 0; t2 < 2; ++t2) {
#pragma unroll
    for (int nt = 0; nt < 16; ++nt) {
#pragma unroll
      for (int r = 0; r < 4; ++r) {
        int i = rowbase + t2 * 16 + q * 4 + r;
        op[(size_t)i * COUT + nt * 16 + n] = acc[t2][nt][r];
      }
    }
  }
}

// ---------- K5: out = (sum_js opart)/(sum_js Dpart) + bias ----------
__global__ void k_final_part(float* __restrict__ out, const float* __restrict__ opart,
                             const float* __restrict__ Dpart, const float* __restrict__ bias) {
  int i = blockIdx.x;
  int c = threadIdx.x;
  float s = 0.f, d = 0.f;
#pragma unroll
  for (int js = 0; js < 8; ++js) {
    s += opart[((size_t)js * NN + i) * COUT + c];
    d += Dpart[(size_t)js * NN + i];
  }
  out[(size_t)i * COUT + c] = s / fmaxf(d, 1e-37f) + bias[c];
}

// ---------- Fallback path (atomics, direct adj) if ws is too small ----------
__global__ __launch_bounds__(256, 2)
void k_attn_atomic(const int* __restrict__ adj, const unsigned short* __restrict__ ht,
                   const float* __restrict__ e1, const float* __restrict__ e2,
                   float* __restrict__ out_num, float* __restrict__ Dbuf) {
  int b = blockIdx.x;
  int rg = b >> 3, js = b & 7;
  int wave = threadIdx.x >> 6, lane = threadIdx.x & 63;
  int n = lane & 15, q = lane >> 4;
  int rowbase = rg * 128 + wave * 32;

  float e1v0 = e1[rowbase + n];
  float e1v1 = e1[rowbase + 16 + n];

  floatx4 acc[2][16];
#pragma unroll
  for (int t = 0; t < 2; ++t)
#pragma unroll
    for (int nt = 0; nt < 16; ++nt) acc[t][nt] = (floatx4){0.f, 0.f, 0.f, 0.f};

  float d0 = 0.f, d1 = 0.f;
  int jbeg = js * 1024;

  for (int ch = 0; ch < 32; ++ch) {
    int j0 = jbeg + ch * 32 + q * 8;
    floatx4 ea = *(const floatx4*)(e2 + j0);
    floatx4 eb = *(const floatx4*)(e2 + j0 + 4);
    float ev[8] = {ea.x, ea.y, ea.z, ea.w, eb.x, eb.y, eb.z, eb.w};

    intx4 A00 = *(const intx4*)(adj + (size_t)(rowbase + n) * NN + j0);
    intx4 A01 = *(const intx4*)(adj + (size_t)(rowbase + n) * NN + j0 + 4);
    intx4 A10 = *(const intx4*)(adj + (size_t)(rowbase + 16 + n) * NN + j0);
    intx4 A11 = *(const intx4*)(adj + (size_t)(rowbase + 16 + n) * NN + j0 + 4);

    float p0[8], p1[8];
#pragma unroll
    for (int jj = 0; jj < 8; ++jj) {
      int av0 = (jj < 4) ? A00[jj] : A01[jj - 4];
      int av1 = (jj < 4) ? A10[jj] : A11[jj - 4];
      float t0 = e1v0 + ev[jj];
      float t1 = e1v1 + ev[jj];
      float f0 = fmaxf(t0, 0.25f * t0);
      float f1 = fmaxf(t1, 0.25f * t1);
      float x0 = __expf(f0 - SHIFT);
      float x1 = __expf(f1 - SHIFT);
      p0[jj] = (av0 != 0) ? x0 : 0.f;
      p1[jj] = (av1 != 0) ? x1 : 0.f;
      d0 += p0[jj];
      d1 += p1[jj];
    }
    short8 af0 = pack8(p0);
    short8 af1 = pack8(p1);

#pragma unroll
    for (int g = 0; g < 2; ++g) {
      short8 bf[8];
#pragma unroll
      for (int t = 0; t < 8; ++t)
        bf[t] = *(const short8*)(ht + (size_t)((g * 8 + t) * 16 + n) * NN + j0);
#pragma unroll
      for (int t = 0; t < 8; ++t) {
        acc[0][g * 8 + t] = __builtin_amdgcn_mfma_f32_16x16x32_bf16(af0, bf[t], acc[0][g * 8 + t], 0, 0, 0);
        acc[1][g * 8 + t] = __builtin_amdgcn_mfma_f32_16x16x32_bf16(af1, bf[t], acc[1][g * 8 + t], 0, 0, 0);
      }
    }
  }

  d0 += __shfl_xor(d0, 16); d0 += __shfl_xor(d0, 32);
  d1 += __shfl_xor(d1, 16); d1 += __shfl_xor(d1, 32);
  if (lane < 16) {
    atomicAdd(Dbuf + rowbase + lane, d0);
    atomicAdd(Dbuf + rowbase + 16 + lane, d1);
  }

#pragma unroll
  for (int t2 = 0; t2 < 2; ++t2) {
#pragma unroll
    for (int nt = 0; nt < 16; ++nt) {
#pragma unroll
      for (int r = 0; r < 4; ++r) {
        int i = rowbase + t2 * 16 + q * 4 + r;
        atomicAdd(out_num + (size_t)i * COUT + nt * 16 + n, acc[t2][nt][r]);
      }
    }
  }
}

__global__ void k_final_atomic(float* __restrict__ out, const float* __restrict__ Dbuf,
                               const float* __restrict__ bias) {
  int idx = blockIdx.x * 256 + threadIdx.x;
  int i = idx >> 8, c = idx & 255;
  float d = fmaxf(Dbuf[i], 1e-37f);
  out[idx] = out[idx] / d + bias[c];
}

// ---------- launch ----------
extern "C" void kernel_launch(void* const* d_in, const int* in_sizes, int n_in,
                              void* d_out, int out_size, void* d_ws, size_t ws_size,
                              hipStream_t stream) {
  const float* input   = (const float*)d_in[0];
  const int*   adj     = (const int*)d_in[1];
  const float* weights = (const float*)d_in[2];
  const float* a1      = (const float*)d_in[3];
  const float* a2      = (const float*)d_in[4];
  const float* bias    = (const float*)d_in[5];
  float* out = (float*)d_out;
  char* ws = (char*)d_ws;

  unsigned short* inA = (unsigned short*)(ws);                 // 8 MB   [8192][512] bf16
  unsigned short* wt  = (unsigned short*)(ws + 8388608);       // 256 KB [256][512] bf16
  unsigned short* ht  = (unsigned short*)(ws + 8650752);       // 4 MB   [256][8192] bf16
  float* e1    = (float*)(ws + 12845056);                      // 32 KB
  float* e2    = (float*)(ws + 12877824);                      // 32 KB
  float* Dpart = (float*)(ws + 12910592);                      // 256 KB [8][8192]
  float* opart = (float*)(ws + 13172736);                      // 64 MB  [8][8192][256]
  const size_t WS_NEEDED_PART = 13172736 + (size_t)8 * NN * COUT * 4;  // ~77 MB
  float* Dbuf = Dpart;

  k_cast_input<<<4096, 256, 0, stream>>>(input, (ushortx4*)inA);
  k_prep_w<<<512, 256, 0, stream>>>(weights, wt);
  k_gemm_h<<<128, 256, 0, stream>>>(inA, wt, a1, a2, ht, e1, e2);

  if (ws_size >= WS_NEEDED_PART) {
    k_attn_fused<<<512, 256, 0, stream>>>(adj, ht, e1, e2, opart, Dpart);
    k_final_part<<<8192, 256, 0, stream>>>(out, opart, Dpart, bias);
  } else {
    hipMemsetAsync(out, 0, (size_t)NN * COUT * sizeof(float), stream);
    hipMemsetAsync(Dbuf, 0, NN * sizeof(float), stream);
    k_attn_atomic<<<512, 256, 0, stream>>>(adj, ht, e1, e2, out, Dbuf);
    k_final_atomic<<<8192, 256, 0, stream>>>(out, Dbuf, bias);
  }
}

// Round 6
// 453.439 us; speedup vs baseline: 1.2510x; 1.0226x over previous
//
#include <hip/hip_runtime.h>

typedef __attribute__((ext_vector_type(8))) short short8;
typedef __attribute__((ext_vector_type(4))) float floatx4;
typedef __attribute__((ext_vector_type(4))) unsigned int uintx4;
typedef __attribute__((ext_vector_type(2))) unsigned int uintx2;
typedef __attribute__((ext_vector_type(4))) int intx4;
typedef __attribute__((ext_vector_type(4))) unsigned short ushortx4;
typedef unsigned int u32;

#define NN 8192
#define KIN 512
#define COUT 256
#define SHIFT 16.0f

#define AS1 __attribute__((address_space(1)))
#define AS3 __attribute__((address_space(3)))

// async global->LDS, 16B per lane; LDS base wave-uniform, lane lands at +lane*16
__device__ __forceinline__ void stage16(const void* g, void* l) {
  __builtin_amdgcn_global_load_lds((const AS1 u32*)g, (AS3 u32*)l, 16, 0, 0);
}

// ---------- helpers ----------
__device__ __forceinline__ unsigned int f2bf(float f) {
  unsigned int u = __float_as_uint(f);
  return (u + 0x7FFFu + ((u >> 16) & 1u)) >> 16;  // RNE round to bf16
}

__device__ __forceinline__ short8 pack8(const float* p) {
  uintx4 w;
  w.x = f2bf(p[0]) | (f2bf(p[1]) << 16);
  w.y = f2bf(p[2]) | (f2bf(p[3]) << 16);
  w.z = f2bf(p[4]) | (f2bf(p[5]) << 16);
  w.w = f2bf(p[6]) | (f2bf(p[7]) << 16);
  union { uintx4 u; short8 s; } cv; cv.u = w;
  return cv.s;
}

// ---------- K1a: cast input fp32 -> bf16 ----------
__global__ void k_cast_input(const float* __restrict__ in, ushortx4* __restrict__ out) {
  int idx = blockIdx.x * 256 + threadIdx.x;
  floatx4 v = ((const floatx4*)in)[idx];
  ushortx4 o;
  o.x = (unsigned short)f2bf(v.x);
  o.y = (unsigned short)f2bf(v.y);
  o.z = (unsigned short)f2bf(v.z);
  o.w = (unsigned short)f2bf(v.w);
  out[idx] = o;
}

// ---------- K1b: weights [512][256] fp32 -> wt [256][512] bf16 (transposed) ----------
__global__ void k_prep_w(const float* __restrict__ w, unsigned short* __restrict__ wt) {
  int idx = blockIdx.x * 256 + threadIdx.x;
  int k = idx >> 8, c = idx & 255;
  wt[c * KIN + k] = (unsigned short)f2bf(w[idx]);
}

// ---------- K2: h = X*W via MFMA; emit ht[256][8192] bf16, e1[8192], e2[8192] ----------
__global__ __launch_bounds__(256)
void k_gemm_h(const unsigned short* __restrict__ inA, const unsigned short* __restrict__ wt,
              const float* __restrict__ a1, const float* __restrict__ a2,
              unsigned short* __restrict__ ht, float* __restrict__ e1, float* __restrict__ e2) {
  int wave = threadIdx.x >> 6;
  int lane = threadIdx.x & 63;
  int n = lane & 15, q = lane >> 4;
  int row0 = blockIdx.x * 64 + wave * 16;
  int mrow = row0 + n;

  floatx4 acc[16];
#pragma unroll
  for (int t = 0; t < 16; ++t) acc[t] = (floatx4){0.f, 0.f, 0.f, 0.f};

  for (int kc = 0; kc < KIN / 32; ++kc) {
    int k0 = kc * 32 + q * 8;
    short8 a = *(const short8*)(inA + (size_t)mrow * KIN + k0);
#pragma unroll
    for (int nt = 0; nt < 16; ++nt) {
      short8 b = *(const short8*)(wt + (size_t)(nt * 16 + n) * KIN + k0);
      acc[nt] = __builtin_amdgcn_mfma_f32_16x16x32_bf16(a, b, acc[nt], 0, 0, 0);
    }
  }

  int i0 = row0 + q * 4;
#pragma unroll
  for (int nt = 0; nt < 16; ++nt) {
    int c = nt * 16 + n;
    uintx2 pk;
    pk.x = f2bf(acc[nt][0]) | (f2bf(acc[nt][1]) << 16);
    pk.y = f2bf(acc[nt][2]) | (f2bf(acc[nt][3]) << 16);
    *(uintx2*)(ht + (size_t)c * NN + i0) = pk;
  }

  float s1[4] = {0.f, 0.f, 0.f, 0.f}, s2[4] = {0.f, 0.f, 0.f, 0.f};
#pragma unroll
  for (int nt = 0; nt < 16; ++nt) {
    float w1 = a1[nt * 16 + n];
    float w2 = a2[nt * 16 + n];
#pragma unroll
    for (int r = 0; r < 4; ++r) {
      s1[r] += acc[nt][r] * w1;
      s2[r] += acc[nt][r] * w2;
    }
  }
#pragma unroll
  for (int m = 1; m < 16; m <<= 1) {
#pragma unroll
    for (int r = 0; r < 4; ++r) {
      s1[r] += __shfl_xor(s1[r], m);
      s2[r] += __shfl_xor(s2[r], m);
    }
  }
  if (n == 0) {
#pragma unroll
    for (int r = 0; r < 4; ++r) {
      e1[i0 + r] = s1[r];
      e2[i0 + r] = s2[r];
    }
  }
}

// ---------- K4: FUSED masked-softmax attention + PV, adj direct-to-LDS ----------
// grid = 64 rowgroups x 8 j-slices = 512 blocks; wave = 32 rows x 256 cols.
// Per chunk: ht tile 16 KB (L2) + adj tile 16 KB (HBM) via global_load_lds,
// double-buffered with FINE-GRAINED vmcnt barriers: the next-chunk prefetch
// stays in flight across the barrier (never s_waitcnt vmcnt(0) in steady state).
__global__ __launch_bounds__(256, 2)
void k_attn_fused(const int* __restrict__ adj, const unsigned short* __restrict__ ht,
                  const float* __restrict__ e1, const float* __restrict__ e2,
                  float* __restrict__ opart, float* __restrict__ Dpart) {
  // LDS: buf0 [ht 16K | adj 16K] buf1 [ht 16K | adj 16K] e2s 4K = 69632 B
  __shared__ __align__(16) char smem[69632];
  float* e2s = (float*)(smem + 65536);

  int b = blockIdx.x;
  int rg = b >> 3, js = b & 7;                       // js = b&7: slice per XCD (L2 locality)
  int wave = threadIdx.x >> 6, lane = threadIdx.x & 63;
  int n = lane & 15, q = lane >> 4;
  int rowblock = rg * 128;
  int rowbase = rowblock + wave * 32;
  int jbeg = js * 1024;

  // e2 slice -> LDS once (first-iteration lgkm wait + barrier covers visibility)
  ((floatx4*)e2s)[threadIdx.x] = *(const floatx4*)(e2 + jbeg + threadIdx.x * 4);

  float e1v0 = e1[rowbase + n];
  float e1v1 = e1[rowbase + 16 + n];

  floatx4 acc[2][16];
#pragma unroll
  for (int t = 0; t < 2; ++t)
#pragma unroll
    for (int nt = 0; nt < 16; ++nt) acc[t][nt] = (floatx4){0.f, 0.f, 0.f, 0.f};

  float d0 = 0.f, d1 = 0.f;

  // stage chunk ch into buf: 8 global_load_lds per wave (4 ht segs + 4 adj rows-groups)
  auto stage = [&](int ch, int buf) {
    int j0g = jbeg + ch * 32;
    char* hbase = smem + buf * 32768;
#pragma unroll
    for (int i = 0; i < 4; ++i) {
      int seg = wave * 256 + i * 64 + lane;
      int c = seg >> 2;
      int j8 = (seg & 3) * 8;
      stage16(ht + (size_t)c * NN + j0g + j8, hbase + (size_t)(wave * 256 + i * 64) * 16);
    }
    char* abase = hbase + 16384 + wave * 4096;
    const int* aw = adj + (size_t)(rowblock + wave * 32) * NN + j0g;
#pragma unroll
    for (int i = 0; i < 4; ++i) {
      stage16(aw + (size_t)(i * 8 + (lane & 7)) * NN + (lane >> 3) * 4, abase + i * 1024);
    }
  };

  int rlo = n & 7, rhi = n >> 3;

  stage(0, 0);

  for (int ch = 0; ch < 32; ++ch) {
    int cur = ch & 1;
    if (ch < 31) {
      stage(ch + 1, cur ^ 1);                        // 8 newest vmcnt items = next chunk
      // wait ONLY for chunk ch's DMAs (all but the 8 newest); prefetch stays in flight
      asm volatile("s_waitcnt vmcnt(8) lgkmcnt(0)" ::: "memory");
    } else {
      asm volatile("s_waitcnt vmcnt(0) lgkmcnt(0)" ::: "memory");
    }
    asm volatile("s_barrier" ::: "memory");          // all waves' chunk-ch tiles landed

    // adj masks from LDS: row n at rhi*1024 + q*256 + rlo*16 (+128 cols+4; +2048 row n+16)
    const char* ab = smem + cur * 32768 + 16384 + wave * 4096;
    intx4 a0a = *(const intx4*)(ab + rhi * 1024 + q * 256 + rlo * 16);
    intx4 a0b = *(const intx4*)(ab + rhi * 1024 + q * 256 + 128 + rlo * 16);
    intx4 a1a = *(const intx4*)(ab + 2048 + rhi * 1024 + q * 256 + rlo * 16);
    intx4 a1b = *(const intx4*)(ab + 2048 + rhi * 1024 + q * 256 + 128 + rlo * 16);

    floatx4 ea = *(const floatx4*)(e2s + ch * 32 + q * 8);
    floatx4 eb = *(const floatx4*)(e2s + ch * 32 + q * 8 + 4);
    float ev[8] = {ea.x, ea.y, ea.z, ea.w, eb.x, eb.y, eb.z, eb.w};

    float p0[8], p1[8];
#pragma unroll
    for (int jj = 0; jj < 8; ++jj) {
      int av0 = (jj < 4) ? a0a[jj] : a0b[jj - 4];
      int av1 = (jj < 4) ? a1a[jj] : a1b[jj - 4];
      float t0 = e1v0 + ev[jj];
      float t1 = e1v1 + ev[jj];
      float f0 = fmaxf(t0, 0.25f * t0);              // leakyrelu (slope 0.25)
      float f1 = fmaxf(t1, 0.25f * t1);
      float x0 = __expf(f0 - SHIFT);                 // fixed shift: exp <= ~0.14 always
      float x1 = __expf(f1 - SHIFT);
      p0[jj] = (av0 != 0) ? x0 : 0.f;
      p1[jj] = (av1 != 0) ? x1 : 0.f;
      d0 += p0[jj];
      d1 += p1[jj];
    }
    short8 af0 = pack8(p0);
    short8 af1 = pack8(p1);

    // B-frags from LDS ht tile: frag(t,n,q) at byte t*1024 + n*64 + q*16
    const short8* lb = (const short8*)(smem + (size_t)cur * 32768);
#pragma unroll
    for (int t = 0; t < 16; ++t) {
      short8 bf = lb[t * 64 + n * 4 + q];
      acc[0][t] = __builtin_amdgcn_mfma_f32_16x16x32_bf16(af0, bf, acc[0][t], 0, 0, 0);
      acc[1][t] = __builtin_amdgcn_mfma_f32_16x16x32_bf16(af1, bf, acc[1][t], 0, 0, 0);
    }

    // end-of-chunk: ds_reads consumed (lgkm ~drained); do NOT drain vmcnt —
    // next-chunk DMAs keep flying across this barrier.
    asm volatile("s_waitcnt lgkmcnt(0)" ::: "memory");
    asm volatile("s_barrier" ::: "memory");
  }

  d0 += __shfl_xor(d0, 16); d0 += __shfl_xor(d0, 32);
  d1 += __shfl_xor(d1, 16); d1 += __shfl_xor(d1, 32);
  if (lane < 16) {
    Dpart[(size_t)js * NN + rowbase + lane] = d0;
    Dpart[(size_t)js * NN + rowbase + 16 + lane] = d1;
  }

  float* op = opart + (size_t)js * NN * COUT;
#pragma unroll
  for (int t2 = 0; t2 < 2; ++t2) {
#pragma unroll
    for (int nt = 0; nt < 16; ++nt) {
#pragma unroll
      for (int r = 0; r < 4; ++r) {
        int i = rowbase + t2 * 16 + q * 4 + r;
        op[(size_t)i * COUT + nt * 16 + n] = acc[t2][nt][r];
      }
    }
  }
}

// ---------- K5: out = (sum_js opart)/(sum_js Dpart) + bias ----------
__global__ void k_final_part(float* __restrict__ out, const float* __restrict__ opart,
                             const float* __restrict__ Dpart, const float* __restrict__ bias) {
  int i = blockIdx.x;
  int c = threadIdx.x;
  float s = 0.f, d = 0.f;
#pragma unroll
  for (int js = 0; js < 8; ++js) {
    s += opart[((size_t)js * NN + i) * COUT + c];
    d += Dpart[(size_t)js * NN + i];
  }
  out[(size_t)i * COUT + c] = s / fmaxf(d, 1e-37f) + bias[c];
}

// ---------- Fallback path (atomics, direct adj) if ws is too small ----------
__global__ __launch_bounds__(256, 2)
void k_attn_atomic(const int* __restrict__ adj, const unsigned short* __restrict__ ht,
                   const float* __restrict__ e1, const float* __restrict__ e2,
                   float* __restrict__ out_num, float* __restrict__ Dbuf) {
  int b = blockIdx.x;
  int rg = b >> 3, js = b & 7;
  int wave = threadIdx.x >> 6, lane = threadIdx.x & 63;
  int n = lane & 15, q = lane >> 4;
  int rowbase = rg * 128 + wave * 32;

  float e1v0 = e1[rowbase + n];
  float e1v1 = e1[rowbase + 16 + n];

  floatx4 acc[2][16];
#pragma unroll
  for (int t = 0; t < 2; ++t)
#pragma unroll
    for (int nt = 0; nt < 16; ++nt) acc[t][nt] = (floatx4){0.f, 0.f, 0.f, 0.f};

  float d0 = 0.f, d1 = 0.f;
  int jbeg = js * 1024;

  for (int ch = 0; ch < 32; ++ch) {
    int j0 = jbeg + ch * 32 + q * 8;
    floatx4 ea = *(const floatx4*)(e2 + j0);
    floatx4 eb = *(const floatx4*)(e2 + j0 + 4);
    float ev[8] = {ea.x, ea.y, ea.z, ea.w, eb.x, eb.y, eb.z, eb.w};

    intx4 A00 = *(const intx4*)(adj + (size_t)(rowbase + n) * NN + j0);
    intx4 A01 = *(const intx4*)(adj + (size_t)(rowbase + n) * NN + j0 + 4);
    intx4 A10 = *(const intx4*)(adj + (size_t)(rowbase + 16 + n) * NN + j0);
    intx4 A11 = *(const intx4*)(adj + (size_t)(rowbase + 16 + n) * NN + j0 + 4);

    float p0[8], p1[8];
#pragma unroll
    for (int jj = 0; jj < 8; ++jj) {
      int av0 = (jj < 4) ? A00[jj] : A01[jj - 4];
      int av1 = (jj < 4) ? A10[jj] : A11[jj - 4];
      float t0 = e1v0 + ev[jj];
      float t1 = e1v1 + ev[jj];
      float f0 = fmaxf(t0, 0.25f * t0);
      float f1 = fmaxf(t1, 0.25f * t1);
      float x0 = __expf(f0 - SHIFT);
      float x1 = __expf(f1 - SHIFT);
      p0[jj] = (av0 != 0) ? x0 : 0.f;
      p1[jj] = (av1 != 0) ? x1 : 0.f;
      d0 += p0[jj];
      d1 += p1[jj];
    }
    short8 af0 = pack8(p0);
    short8 af1 = pack8(p1);

#pragma unroll
    for (int g = 0; g < 2; ++g) {
      short8 bf[8];
#pragma unroll
      for (int t = 0; t < 8; ++t)
        bf[t] = *(const short8*)(ht + (size_t)((g * 8 + t) * 16 + n) * NN + j0);
#pragma unroll
      for (int t = 0; t < 8; ++t) {
        acc[0][g * 8 + t] = __builtin_amdgcn_mfma_f32_16x16x32_bf16(af0, bf[t], acc[0][g * 8 + t], 0, 0, 0);
        acc[1][g * 8 + t] = __builtin_amdgcn_mfma_f32_16x16x32_bf16(af1, bf[t], acc[1][g * 8 + t], 0, 0, 0);
      }
    }
  }

  d0 += __shfl_xor(d0, 16); d0 += __shfl_xor(d0, 32);
  d1 += __shfl_xor(d1, 16); d1 += __shfl_xor(d1, 32);
  if (lane < 16) {
    atomicAdd(Dbuf + rowbase + lane, d0);
    atomicAdd(Dbuf + rowbase + 16 + lane, d1);
  }

#pragma unroll
  for (int t2 = 0; t2 < 2; ++t2) {
#pragma unroll
    for (int nt = 0; nt < 16; ++nt) {
#pragma unroll
      for (int r = 0; r < 4; ++r) {
        int i = rowbase + t2 * 16 + q * 4 + r;
        atomicAdd(out_num + (size_t)i * COUT + nt * 16 + n, acc[t2][nt][r]);
      }
    }
  }
}

__global__ void k_final_atomic(float* __restrict__ out, const float* __restrict__ Dbuf,
                               const float* __restrict__ bias) {
  int idx = blockIdx.x * 256 + threadIdx.x;
  int i = idx >> 8, c = idx & 255;
  float d = fmaxf(Dbuf[i], 1e-37f);
  out[idx] = out[idx] / d + bias[c];
}

// ---------- launch ----------
extern "C" void kernel_launch(void* const* d_in, const int* in_sizes, int n_in,
                              void* d_out, int out_size, void* d_ws, size_t ws_size,
                              hipStream_t stream) {
  const float* input   = (const float*)d_in[0];
  const int*   adj     = (const int*)d_in[1];
  const float* weights = (const float*)d_in[2];
  const float* a1      = (const float*)d_in[3];
  const float* a2      = (const float*)d_in[4];
  const float* bias    = (const float*)d_in[5];
  float* out = (float*)d_out;
  char* ws = (char*)d_ws;

  unsigned short* inA = (unsigned short*)(ws);                 // 8 MB   [8192][512] bf16
  unsigned short* wt  = (unsigned short*)(ws + 8388608);       // 256 KB [256][512] bf16
  unsigned short* ht  = (unsigned short*)(ws + 8650752);       // 4 MB   [256][8192] bf16
  float* e1    = (float*)(ws + 12845056);                      // 32 KB
  float* e2    = (float*)(ws + 12877824);                      // 32 KB
  float* Dpart = (float*)(ws + 12910592);                      // 256 KB [8][8192]
  float* opart = (float*)(ws + 13172736);                      // 64 MB  [8][8192][256]
  const size_t WS_NEEDED_PART = 13172736 + (size_t)8 * NN * COUT * 4;  // ~77 MB
  float* Dbuf = Dpart;

  k_cast_input<<<4096, 256, 0, stream>>>(input, (ushortx4*)inA);
  k_prep_w<<<512, 256, 0, stream>>>(weights, wt);
  k_gemm_h<<<128, 256, 0, stream>>>(inA, wt, a1, a2, ht, e1, e2);

  if (ws_size >= WS_NEEDED_PART) {
    k_attn_fused<<<512, 256, 0, stream>>>(adj, ht, e1, e2, opart, Dpart);
    k_final_part<<<8192, 256, 0, stream>>>(out, opart, Dpart, bias);
  } else {
    hipMemsetAsync(out, 0, (size_t)NN * COUT * sizeof(float), stream);
    hipMemsetAsync(Dbuf, 0, NN * sizeof(float), stream);
    k_attn_atomic<<<512, 256, 0, stream>>>(adj, ht, e1, e2, out, Dbuf);
    k_final_atomic<<<8192, 256, 0, stream>>>(out, Dbuf, bias);
  }
}